// Round 1
// baseline (316.359 us; speedup 1.0000x reference)
//
#include <hip/hip_runtime.h>
#include <math.h>

#define BATCH 16
#define CH    64
#define HH    128
#define WW    128
#define PLANE (HH*WW)          // 16384
#define LROW  144              // padded row stride (8 left + 128 + 8 right)
#define LROWS 138              // padded rows (5 + 128 + 5)
#define OUT0  (BATCH*3*CH*PLANE)  // 50331648

// ws float layout: [0,1024) M ; [1024,2048) ps ; [2048) S ; [3072) Sw ;
// [4096) Sh ; [5120) Scol ; [6144) Srow

// ---------------- Kernel 1: per-(b,c) max of x -> M, ps ----------------
__global__ __launch_bounds__(256) void k_max(const float* __restrict__ x,
                                             float* __restrict__ ws) {
    int bid = blockIdx.x;                    // 0..1023 = b*64+c
    const float4* xp = (const float4*)(x + (size_t)bid * PLANE);
    int tid = threadIdx.x;
    float m = -INFINITY;
#pragma unroll
    for (int i = 0; i < 16; i++) {
        float4 v = xp[i * 256 + tid];
        m = fmaxf(m, fmaxf(fmaxf(v.x, v.y), fmaxf(v.z, v.w)));
    }
#pragma unroll
    for (int off = 32; off; off >>= 1) m = fmaxf(m, __shfl_xor(m, off, 64));
    __shared__ float sm[4];
    int wid = tid >> 6, lane = tid & 63;
    if (lane == 0) sm[wid] = m;
    __syncthreads();
    if (tid == 0) {
        float mm = fmaxf(fmaxf(sm[0], sm[1]), fmaxf(sm[2], sm[3]));
        float ps = 1.0f / (1.0f + expf(-mm));
        ws[bid] = ps - 0.01f;        // M
        ws[1024 + bid] = ps;         // ps
    }
}

// ---------------- Kernel 2: fields (unmasked) + per-plane sums ----------------
__global__ __launch_bounds__(256) void k_fields(
    const float* __restrict__ x,
    const float* __restrict__ w_bbx, const float* __restrict__ w_width,
    const float* __restrict__ w_width_sh, const float* __restrict__ w_height,
    const float* __restrict__ w_height_sh,
    float* __restrict__ ws, float* __restrict__ out) {
    __shared__ float xs[LROWS * LROW];
    __shared__ float red[4 * 5];
    int bid = blockIdx.x;                  // b*64 + c
    int b = bid >> 6, c = bid & 63;
    int tid = threadIdx.x;

    // zero-pad whole LDS plane, then fill interior
    for (int i = tid; i < LROWS * LROW; i += 256) xs[i] = 0.0f;
    __syncthreads();
    const float* xp = x + (size_t)bid * PLANE;
#pragma unroll
    for (int i = 0; i < 16; i++) {
        int idx = i * 256 + tid;           // float4 index in plane
        int p = idx * 4;
        int y = p >> 7, xc = p & 127;
        float4 v = ((const float4*)xp)[idx];
        *(float4*)&xs[(y + 5) * LROW + xc + 8] = v;
    }
    float wk[11], hk[11];
#pragma unroll
    for (int k = 0; k < 11; k++) {
        wk[k] = w_width[c * 11 + k];
        hk[k] = w_height[c * 11 + k];
    }
    float cb = w_bbx[c];
    float cw = 128.0f * w_width_sh[c] * cb;   // * W
    float chs = 128.0f * w_height_sh[c] * cb; // * H
    float M = ws[bid];
    __syncthreads();

    float S = 0.f, Sw = 0.f, Sh = 0.f, Scol = 0.f, Srow = 0.f;
    float* outS = out + (size_t)(b * 192 + c) * PLANE;
    float* outW = out + (size_t)(b * 192 + 64 + c) * PLANE;
    float* outH = out + (size_t)(b * 192 + 128 + c) * PLANE;

    for (int g = 0; g < 16; g++) {
        int idx = g * 256 + tid;
        int p = idx * 4;
        int y = p >> 7, xc = p & 127;
        // vertical 11-tap conv on 4 adjacent columns
        float4 vx;                          // center row (k=5) = raw x
        float hx = 0.f, hy = 0.f, hz = 0.f, hw = 0.f;
#pragma unroll
        for (int k = 0; k < 11; k++) {
            float4 v = *(const float4*)&xs[(y + k) * LROW + xc + 8];
            if (k == 5) vx = v;
            hx += v.x * hk[k]; hy += v.y * hk[k];
            hz += v.z * hk[k]; hw += v.w * hk[k];
        }
        // horizontal window: padded cols xc..xc+19 (orig xc-8 .. xc+11)
        float wbuf[20];
        {
            float4 a0 = *(const float4*)&xs[(y + 5) * LROW + xc + 0];
            float4 a1 = *(const float4*)&xs[(y + 5) * LROW + xc + 4];
            float4 a3 = *(const float4*)&xs[(y + 5) * LROW + xc + 12];
            float4 a4 = *(const float4*)&xs[(y + 5) * LROW + xc + 16];
            wbuf[0] = a0.x;  wbuf[1] = a0.y;  wbuf[2] = a0.z;  wbuf[3] = a0.w;
            wbuf[4] = a1.x;  wbuf[5] = a1.y;  wbuf[6] = a1.z;  wbuf[7] = a1.w;
            wbuf[8] = vx.x;  wbuf[9] = vx.y;  wbuf[10] = vx.z; wbuf[11] = vx.w;
            wbuf[12] = a3.x; wbuf[13] = a3.y; wbuf[14] = a3.z; wbuf[15] = a3.w;
            wbuf[16] = a4.x; wbuf[17] = a4.y; wbuf[18] = a4.z; wbuf[19] = a4.w;
        }
        float wo[4];
#pragma unroll
        for (int j = 0; j < 4; j++) {
            float acc = 0.f;
#pragma unroll
            for (int k = 0; k < 11; k++) acc += wbuf[j + 3 + k] * wk[k];
            wo[j] = acc * cw;
        }
        float ho[4] = {hx * chs, hy * chs, hz * chs, hw * chs};
        float xv[4] = {vx.x, vx.y, vx.z, vx.w};
        float sc[4];
#pragma unroll
        for (int j = 0; j < 4; j++) {
            float sx = 1.0f / (1.0f + expf(-xv[j]));
            sc[j] = (sx > M) ? xv[j] : 0.0f;
        }
        float s4 = sc[0] + sc[1] + sc[2] + sc[3];
        S += s4;
        Srow += (float)y * s4;
#pragma unroll
        for (int j = 0; j < 4; j++) {
            Sw += wo[j] * sc[j];
            Sh += ho[j] * sc[j];
            Scol += (float)(xc + j) * sc[j];
        }
        float4 o;
        o.x = sc[0]; o.y = sc[1]; o.z = sc[2]; o.w = sc[3];
        ((float4*)outS)[idx] = o;
        o.x = wo[0]; o.y = wo[1]; o.z = wo[2]; o.w = wo[3];
        ((float4*)outW)[idx] = o;
        o.x = ho[0]; o.y = ho[1]; o.z = ho[2]; o.w = ho[3];
        ((float4*)outH)[idx] = o;
    }
    // block-reduce the 5 sums (block owns the whole plane: plain store)
#pragma unroll
    for (int off = 32; off; off >>= 1) {
        S    += __shfl_xor(S, off, 64);
        Sw   += __shfl_xor(Sw, off, 64);
        Sh   += __shfl_xor(Sh, off, 64);
        Scol += __shfl_xor(Scol, off, 64);
        Srow += __shfl_xor(Srow, off, 64);
    }
    int wid = tid >> 6, lane = tid & 63;
    if (lane == 0) {
        red[wid * 5 + 0] = S;   red[wid * 5 + 1] = Sw;
        red[wid * 5 + 2] = Sh;  red[wid * 5 + 3] = Scol;
        red[wid * 5 + 4] = Srow;
    }
    __syncthreads();
    if (tid == 0) {
        float a0 = 0, a1 = 0, a2 = 0, a3 = 0, a4 = 0;
#pragma unroll
        for (int w2 = 0; w2 < 4; w2++) {
            a0 += red[w2 * 5 + 0]; a1 += red[w2 * 5 + 1];
            a2 += red[w2 * 5 + 2]; a3 += red[w2 * 5 + 3];
            a4 += red[w2 * 5 + 4];
        }
        ws[2048 + bid] = a0;   // S
        ws[3072 + bid] = a1;   // Sw
        ws[4096 + bid] = a2;   // Sh
        ws[5120 + bid] = a3;   // Scol
        ws[6144 + bid] = a4;   // Srow
    }
}

// ---------------- Kernel 3: channel-max mask, in place ----------------
__global__ __launch_bounds__(256) void k_mask(float* __restrict__ out) {
    __shared__ float T[64 * 256];
    int bid = blockIdx.x;                   // b*64 + tile
    int b = bid >> 6;
    int p0 = (bid & 63) * 256;
    int tid = threadIdx.x;
    for (int f = 0; f < 3; f++) {
        size_t base = ((size_t)b * 192 + (size_t)f * 64) * PLANE + p0;
        // stage 64 channels x 256 pixels (coalesced float4)
#pragma unroll
        for (int ci = 0; ci < 16; ci++) {
            int ch = ci * 4 + (tid >> 6);
            int px = (tid & 63) * 4;
            float4 v = *(const float4*)&out[base + (size_t)ch * PLANE + px];
            *(float4*)&T[ch * 256 + px] = v;
        }
        __syncthreads();
        float m = -INFINITY;
#pragma unroll
        for (int cc = 0; cc < 64; cc++) m = fmaxf(m, T[cc * 256 + tid]);
#pragma unroll
        for (int cc = 0; cc < 64; cc++) {
            float v = T[cc * 256 + tid];
            T[cc * 256 + tid] = (v == m) ? v : 0.0f;
        }
        __syncthreads();
#pragma unroll
        for (int ci = 0; ci < 16; ci++) {
            int ch = ci * 4 + (tid >> 6);
            int px = (tid & 63) * 4;
            float4 v = *(const float4*)&T[ch * 256 + px];
            *(float4*)&out[base + (size_t)ch * PLANE + px] = v;
        }
        __syncthreads();
    }
}

// ---------------- Kernel 4: bbox rows ----------------
__global__ __launch_bounds__(256) void k_bbox(const float* __restrict__ ws,
                                              float* __restrict__ out) {
    int idx = blockIdx.x * 256 + threadIdx.x;
    if (idx >= 1024) return;
    int b = idx >> 6;
    float S    = ws[2048 + idx];
    float Sw   = ws[3072 + idx];
    float Sh   = ws[4096 + idx];
    float Scol = ws[5120 + idx];
    float Srow = ws[6144 + idx];
    float ps   = ws[1024 + idx];
    float inv = 1.0f / S;
    float wsv = Sw * inv, hsv = Sh * inv;
    float x1 = Scol * inv - 0.5f * wsv;
    float y1 = Srow * inv - 0.5f * hsv;
    float* o = out + OUT0 + (size_t)idx * 6;
    o[0] = (float)b;
    o[1] = x1;
    o[2] = y1;
    o[3] = x1 + wsv;
    o[4] = y1 + hsv;
    o[5] = ps;
}

extern "C" void kernel_launch(void* const* d_in, const int* in_sizes, int n_in,
                              void* d_out, int out_size, void* d_ws, size_t ws_size,
                              hipStream_t stream) {
    const float* x          = (const float*)d_in[0];
    const float* w_bbx      = (const float*)d_in[1];
    const float* w_width    = (const float*)d_in[2];
    const float* w_width_sh = (const float*)d_in[3];
    const float* w_height   = (const float*)d_in[4];
    const float* w_height_sh= (const float*)d_in[5];
    float* out = (float*)d_out;
    float* ws  = (float*)d_ws;

    k_max<<<dim3(1024), dim3(256), 0, stream>>>(x, ws);
    k_fields<<<dim3(1024), dim3(256), 0, stream>>>(
        x, w_bbx, w_width, w_width_sh, w_height, w_height_sh, ws, out);
    k_mask<<<dim3(1024), dim3(256), 0, stream>>>(out);
    k_bbox<<<dim3(4), dim3(256), 0, stream>>>(ws, out);
}